// Round 19
// baseline (65.009 us; speedup 1.0000x reference)
//
#include <hip/hip_runtime.h>
#include <math.h>

#define KS 11
#define CHUNK 22      // output rows per block = 2 x 11 (static ring phases)
#define GRIDY 24      // 24*22 = 528 >= 512; tail rows masked out of the sum
#define IMW 512
#define IMH 512

// g: 11-tap Gaussian (h-conv, uniform scalar weights);
// gm = g/sqrt(2) (vertical mean chain), gs = g/2 (vertical second-moment chain)
struct GWargs { float g[KS]; float gm[KS]; float gs[KS]; };

typedef int   v4i __attribute__((ext_vector_type(4)));
typedef float f2  __attribute__((ext_vector_type(2)));
typedef float f4  __attribute__((ext_vector_type(4)));

// CK-style direct binding to the raw buffer load intrinsic.
__device__ f2 raw_buf_load_v2(v4i srsrc, int voffset, int soffset, int aux)
    __asm("llvm.amdgcn.raw.buffer.load.v2f32");

// SRD over ONE image row. nrec = IMW*4 for valid rows, 0 for out-of-image
// rows (all loads return 0 -> vertical zero-padding, branchless). Horizontal
// zero-padding: per-dword bounds checks. p=t=0 -> s=d=0 under the transform.
__device__ inline v4i make_row_srd(const float* row, int nrec) {
    union { const float* p; unsigned u[2]; } a; a.p = row;
    v4i r;
    r.x = (int)a.u[0];
    r.y = (int)a.u[1];
    r.z = nrec;             // num_records (bytes, stride==0)
    r.w = 0x00020000;       // raw untyped dword access
    return r;
}

__device__ inline f2 ffma2(f2 a, f2 b, f2 c) {
    return __builtin_elementwise_fma(a, b, c);
}

// s/d-transformed SSIM (4 conv chains), wave-private LDS row cache storing
// f2 {s,d} per column; exact 11-col b64 windows (conflict-free). All four
// FMA chains are tree-split into two halves (fmaf isn't reassociable
// without fast-math, so we do it manually) to halve dependence latency.
// 2304 blocks (9/CU) double wave overlap vs CHUNK 44.
__global__ __launch_bounds__(256, 1) void ssim_col_kernel(
    const float* __restrict__ pred, const float* __restrict__ target,
    float* __restrict__ partial, GWargs gw)
{
    const int tid  = threadIdx.x;
    const int wid  = tid >> 6;
    const int lane = tid & 63;
    const int x    = blockIdx.x * 256 + tid;        // output column, 0..511
    const int wx0  = blockIdx.x * 256 + wid * 64;   // wave's first column
    const int y0   = blockIdx.y * CHUNK;            // first output row
    const int bc   = blockIdx.z;
    const float* pimg = pred   + (size_t)bc * (IMH * IMW);
    const float* timg = target + (size_t)bc * (IMH * IMW);

    // [wave][parity][f2 {s,d} of col E+i], E = wx0-8; 128 cols per row
    __shared__ f2 rbuf[4][2][128];     // 8 KiB
    __shared__ float wsum[4];

    // coalesced global byte offset: lane loads cols E+2*lane, E+2*lane+1
    const int vgb = (wx0 - 8 + 2 * lane) * 4;
    // f2 index of window start: col x-5 = E + (lane+3)
    const int w0 = lane + 3;

    // ring: hA = {h(s),h(d)}, hB = {h(s^2),h(d^2)}; slot(row r) = (r-y0+5)%11
    f2 hA[KS], hB[KS];

#define LOADROW(LP, LT, YI)                                                 \
    {                                                                       \
        const int yi = (YI);                                                \
        const int nrec = ((unsigned)yi < (unsigned)IMH) ? (IMW * 4) : 0;    \
        const int yc = yi < 0 ? 0 : (yi > IMH - 1 ? IMH - 1 : yi);          \
        const v4i ps = make_row_srd(pimg + (size_t)yc * IMW, nrec);         \
        const v4i ts = make_row_srd(timg + (size_t)yc * IMW, nrec);         \
        LP = raw_buf_load_v2(ps, vgb, 0, 0);                                \
        LT = raw_buf_load_v2(ts, vgb, 0, 0);                                \
    }

    // pack two columns of {p,t} into {s0,d0,s1,d1} and store as one f4
#define SDWRITE(PAR, LP, LT)                                                \
    *(f4*)&rbuf[wid][PAR][2 * lane] =                                       \
        (f4){(LP).x + (LT).x, (LP).x - (LT).x,                              \
             (LP).y + (LT).y, (LP).y - (LT).y};

    // read the exact 11-f2 window of parity PAR into F0..F10 (locals)
#define READWIN(PAR)                                                        \
        const f2* rb_ = &rbuf[wid][PAR][w0];                                \
        const f2 F0 = rb_[0], F1 = rb_[1], F2 = rb_[2], F3 = rb_[3];        \
        const f2 F4 = rb_[4], F5 = rb_[5], F6 = rb_[6], F7 = rb_[7];        \
        const f2 F8 = rb_[8], F9 = rb_[9], F10 = rb_[10];

#define HTAPa(F, J)                                                         \
    {   const f2 gj = {gw.g[J], gw.g[J]};                                   \
        A1 = ffma2(gj, F, A1);  B1 = ffma2(gj, F * F, B1); }
#define HTAPb(F, J)                                                         \
    {   const f2 gj = {gw.g[J], gw.g[J]};                                   \
        A2 = ffma2(gj, F, A2);  B2 = ffma2(gj, F * F, B2); }

    // h-conv F0..F10 into ring slot S; two half-chains + combine
#define HCONV(S)                                                            \
    {                                                                       \
        f2 A1, B1, A2, B2;                                                  \
        {   const f2 g0 = {gw.g[0], gw.g[0]};                               \
            A1 = g0 * F0; B1 = A1 * F0; }                                   \
        {   const f2 g6 = {gw.g[6], gw.g[6]};                               \
            A2 = g6 * F6; B2 = A2 * F6; }                                   \
        HTAPa(F1, 1)  HTAPa(F2, 2)  HTAPa(F3, 3)                            \
        HTAPa(F4, 4)  HTAPa(F5, 5)                                          \
        HTAPb(F7, 7)  HTAPb(F8, 8)  HTAPb(F9, 9)  HTAPb(F10, 10)            \
        hA[S] = A1 + A2; hB[S] = B1 + B2;                                   \
    }

    // Prologue: rows y0-5 .. y0+5 into slots 0..10 (same-step round trip,
    // one-time cost).
    f2 LpA, LtA, LpB, LtB;
    #pragma unroll
    for (int i = 0; i < KS; ++i) {
        LOADROW(LpA, LtA, y0 - 5 + i)
        SDWRITE(i & 1, LpA, LtA)
        { READWIN(i & 1) HCONV(i) }
    }
    // Pipeline priming: buf[0] <- row y0+6 ; regset1 <- row y0+7.
    LOADROW(LpA, LtA, y0 + 6)
    SDWRITE(0, LpA, LtA)
    LOADROW(LpB, LtB, y0 + 7)

    const float C1 = 1e-4f, C2 = 9e-4f;
    float acc = 0.f;

    // Main step u (output row y0+u):
    //  1. issue global loads for row u+8 into regset u&1
    //  2. ds_write regset (u+1)&1 (row u+7, loaded last step) -> buf[(u+1)&1]
    //  3. read row u+6's 11-col window from buf[u&1] (written last step)
    //  4. vertical + SSIM for output u (covers the reads; split chains)
    //  5. h-conv F -> ring slot u%11
    #pragma unroll
    for (int u = 0; u < CHUNK; ++u) {
        if ((u & 1) == 0) {
            LOADROW(LpA, LtA, y0 + u + 8)
            SDWRITE(1, LpB, LtB)
        } else {
            LOADROW(LpB, LtB, y0 + u + 8)
            SDWRITE(0, LpA, LtA)
        }

        READWIN(u & 1)

        // vertical with folded scales (gm = g/sqrt2, gs = g/2), split chains
        f2 M1 = {0.f, 0.f}, S21 = {0.f, 0.f};
        f2 M2 = {0.f, 0.f}, S22 = {0.f, 0.f};
        #pragma unroll
        for (int j = 0; j < 6; ++j) {
            M1  = ffma2((f2){gw.gm[j], gw.gm[j]}, hA[(u + j) % KS], M1);
            S21 = ffma2((f2){gw.gs[j], gw.gs[j]}, hB[(u + j) % KS], S21);
        }
        #pragma unroll
        for (int j = 6; j < KS; ++j) {
            M2  = ffma2((f2){gw.gm[j], gw.gm[j]}, hA[(u + j) % KS], M2);
            S22 = ffma2((f2){gw.gs[j], gw.gs[j]}, hB[(u + j) % KS], S22);
        }
        const f2 M = M1 + M2, S2 = S21 + S22;
        const float xs = M.x * M.x, xd = M.y * M.y;
        const float a  = xs - xd;              // 2 mu1 mu2
        const float b  = xs + xd;              // mu1^2 + mu2^2
        const float p  = S2.x - S2.y;          // 2 E[pt]
        const float q  = S2.x + S2.y;          // E[p^2] + E[t^2]
        const float num = (a + C1) * (p - a + C2);
        const float den = (b + C1) * (q - b + C2);
        const float val = num * __builtin_amdgcn_rcpf(den);
        // mask output rows beyond the image (block y=23 covers 506..527)
        acc += (y0 + u < IMH) ? val : 0.f;

        HCONV(u % KS)
    }
#undef LOADROW
#undef SDWRITE
#undef READWIN
#undef HTAPa
#undef HTAPb
#undef HCONV

    // Block reduction: wave shfl, then cross-wave via tiny LDS.
    #pragma unroll
    for (int off = 32; off > 0; off >>= 1) acc += __shfl_down(acc, off, 64);
    if (lane == 0) wsum[wid] = acc;
    __syncthreads();
    if (tid == 0) {
        atomicAdd(partial, wsum[0] + wsum[1] + wsum[2] + wsum[3]);
    }
}

__global__ void ssim_final_kernel(const float* __restrict__ partial,
                                  float* __restrict__ out, float invN)
{
    out[0] = 1.f - partial[0] * invN;
}

extern "C" void kernel_launch(void* const* d_in, const int* in_sizes, int n_in,
                              void* d_out, int out_size, void* d_ws, size_t ws_size,
                              hipStream_t stream) {
    const float* pred   = (const float*)d_in[0];
    const float* target = (const float*)d_in[1];
    float* out = (float*)d_out;
    float* partial = (float*)d_ws;

    const int B = 16, C = 3;
    const float invN = 1.0f / ((float)B * C * IMH * IMW);

    // separable 1-D Gaussian, same formula as reference (sigma=1.5, 11 taps)
    GWargs gw;
    {
        float s = 0.f;
        for (int i = 0; i < KS; ++i) {
            double e = exp(-((double)((i - 5) * (i - 5))) / (2.0 * 1.5 * 1.5));
            gw.g[i] = (float)e;
            s += gw.g[i];
        }
        for (int i = 0; i < KS; ++i) {
            gw.g[i]  /= s;
            gw.gm[i]  = gw.g[i] * 0.70710678118654752f;   // g / sqrt(2)
            gw.gs[i]  = gw.g[i] * 0.5f;                   // g / 2
        }
    }

    hipMemsetAsync(partial, 0, sizeof(float), stream);

    dim3 grid(IMW / 256, GRIDY, B * C);   // 2 x 24 x 48 = 2304 blocks
    dim3 block(256);
    ssim_col_kernel<<<grid, block, 0, stream>>>(pred, target, partial, gw);
    ssim_final_kernel<<<1, 1, 0, stream>>>(partial, out, invN);
}

// Round 20
// 64.524 us; speedup vs baseline: 1.0075x; 1.0075x over previous
//
#include <hip/hip_runtime.h>
#include <math.h>

#define KS 11
#define CHUNK 44      // output rows per block; 2 x 22 steps (lcm(2,11) static phases)
#define GRIDY 12      // 12*44 = 528 >= 512; tail rows masked out of the sum
#define IMW 512
#define IMH 512

// g: 11-tap Gaussian (h-conv, uniform scalar weights);
// gm = g/sqrt(2) (vertical mean chain), gs = g/2 (vertical second-moment chain)
struct GWargs { float g[KS]; float gm[KS]; float gs[KS]; };

typedef int   v4i __attribute__((ext_vector_type(4)));
typedef float f2  __attribute__((ext_vector_type(2)));
typedef float f4  __attribute__((ext_vector_type(4)));

// CK-style direct binding to the raw buffer load intrinsic.
__device__ f2 raw_buf_load_v2(v4i srsrc, int voffset, int soffset, int aux)
    __asm("llvm.amdgcn.raw.buffer.load.v2f32");

// SRD over ONE image row. nrec = IMW*4 for valid rows, 0 for out-of-image
// rows (all loads return 0 -> vertical zero-padding, branchless). Horizontal
// zero-padding: per-dword bounds checks. p=t=0 -> s=d=0 under the transform.
__device__ inline v4i make_row_srd(const float* row, int nrec) {
    union { const float* p; unsigned u[2]; } a; a.p = row;
    v4i r;
    r.x = (int)a.u[0];
    r.y = (int)a.u[1];
    r.z = nrec;             // num_records (bytes, stride==0)
    r.w = 0x00020000;       // raw untyped dword access
    return r;
}

__device__ inline f2 ffma2(f2 a, f2 b, f2 c) {
    return __builtin_elementwise_fma(a, b, c);
}

// s/d-transformed SSIM (4 conv chains), wave-private LDS row cache storing
// f2 {s,d} per column; exact 11-col b64 windows (conflict-free). All four
// FMA chains tree-split into two halves (fmaf isn't reassociable without
// fast-math) to halve dependence latency. Low-redundancy grid (CHUNK 44:
// 1.30 ingests/output — R19 showed the split pays only when redundancy
// doesn't rise with it).
__global__ __launch_bounds__(256, 1) void ssim_col_kernel(
    const float* __restrict__ pred, const float* __restrict__ target,
    float* __restrict__ partial, GWargs gw)
{
    const int tid  = threadIdx.x;
    const int wid  = tid >> 6;
    const int lane = tid & 63;
    const int x    = blockIdx.x * 256 + tid;        // output column, 0..511
    const int wx0  = blockIdx.x * 256 + wid * 64;   // wave's first column
    const int y0   = blockIdx.y * CHUNK;            // first output row
    const int bc   = blockIdx.z;
    const float* pimg = pred   + (size_t)bc * (IMH * IMW);
    const float* timg = target + (size_t)bc * (IMH * IMW);

    // [wave][parity][f2 {s,d} of col E+i], E = wx0-8; 128 cols per row
    __shared__ f2 rbuf[4][2][128];     // 8 KiB
    __shared__ float wsum[4];

    // coalesced global byte offset: lane loads cols E+2*lane, E+2*lane+1
    const int vgb = (wx0 - 8 + 2 * lane) * 4;
    // f2 index of window start: col x-5 = E + (lane+3)
    const int w0 = lane + 3;

    // ring: hA = {h(s),h(d)}, hB = {h(s^2),h(d^2)}; slot(row r) = (r-y0+5)%11
    f2 hA[KS], hB[KS];

#define LOADROW(LP, LT, YI)                                                 \
    {                                                                       \
        const int yi = (YI);                                                \
        const int nrec = ((unsigned)yi < (unsigned)IMH) ? (IMW * 4) : 0;    \
        const int yc = yi < 0 ? 0 : (yi > IMH - 1 ? IMH - 1 : yi);          \
        const v4i ps = make_row_srd(pimg + (size_t)yc * IMW, nrec);         \
        const v4i ts = make_row_srd(timg + (size_t)yc * IMW, nrec);         \
        LP = raw_buf_load_v2(ps, vgb, 0, 0);                                \
        LT = raw_buf_load_v2(ts, vgb, 0, 0);                                \
    }

    // pack two columns of {p,t} into {s0,d0,s1,d1} and store as one f4
#define SDWRITE(PAR, LP, LT)                                                \
    *(f4*)&rbuf[wid][PAR][2 * lane] =                                       \
        (f4){(LP).x + (LT).x, (LP).x - (LT).x,                              \
             (LP).y + (LT).y, (LP).y - (LT).y};

    // read the exact 11-f2 window of parity PAR into F0..F10 (locals)
#define READWIN(PAR)                                                        \
        const f2* rb_ = &rbuf[wid][PAR][w0];                                \
        const f2 F0 = rb_[0], F1 = rb_[1], F2 = rb_[2], F3 = rb_[3];        \
        const f2 F4 = rb_[4], F5 = rb_[5], F6 = rb_[6], F7 = rb_[7];        \
        const f2 F8 = rb_[8], F9 = rb_[9], F10 = rb_[10];

#define HTAPa(F, J)                                                         \
    {   const f2 gj = {gw.g[J], gw.g[J]};                                   \
        A1 = ffma2(gj, F, A1);  B1 = ffma2(gj, F * F, B1); }
#define HTAPb(F, J)                                                         \
    {   const f2 gj = {gw.g[J], gw.g[J]};                                   \
        A2 = ffma2(gj, F, A2);  B2 = ffma2(gj, F * F, B2); }

    // h-conv F0..F10 into ring slot S; two half-chains + combine
#define HCONV(S)                                                            \
    {                                                                       \
        f2 A1, B1, A2, B2;                                                  \
        {   const f2 g0 = {gw.g[0], gw.g[0]};                               \
            A1 = g0 * F0; B1 = A1 * F0; }                                   \
        {   const f2 g6 = {gw.g[6], gw.g[6]};                               \
            A2 = g6 * F6; B2 = A2 * F6; }                                   \
        HTAPa(F1, 1)  HTAPa(F2, 2)  HTAPa(F3, 3)                            \
        HTAPa(F4, 4)  HTAPa(F5, 5)                                          \
        HTAPb(F7, 7)  HTAPb(F8, 8)  HTAPb(F9, 9)  HTAPb(F10, 10)            \
        hA[S] = A1 + A2; hB[S] = B1 + B2;                                   \
    }

    // Prologue: rows y0-5 .. y0+5 into slots 0..10 (same-step round trip,
    // one-time cost).
    f2 LpA, LtA, LpB, LtB;
    #pragma unroll
    for (int i = 0; i < KS; ++i) {
        LOADROW(LpA, LtA, y0 - 5 + i)
        SDWRITE(i & 1, LpA, LtA)
        { READWIN(i & 1) HCONV(i) }
    }
    // Pipeline priming: buf[0] <- row y0+6 ; regset1 <- row y0+7.
    LOADROW(LpA, LtA, y0 + 6)
    SDWRITE(0, LpA, LtA)
    LOADROW(LpB, LtB, y0 + 7)

    const float C1 = 1e-4f, C2 = 9e-4f;
    float acc = 0.f;

    // Main step k (output row y0+k):
    //  1. issue global loads for row k+8 into regset k&1
    //  2. ds_write regset (k+1)&1 (row k+7, loaded last step) -> buf[(k+1)&1]
    //  3. read row k+6's 11-col window from buf[k&1] (written last step)
    //  4. vertical + SSIM for output k (covers the reads; split chains)
    //  5. h-conv F -> ring slot k%11
    for (int o = 0; o < 2; ++o) {
        #pragma unroll
        for (int u = 0; u < 22; ++u) {
            const int k = 22 * o + u;

            if ((u & 1) == 0) {
                LOADROW(LpA, LtA, y0 + k + 8)
                SDWRITE(1, LpB, LtB)
            } else {
                LOADROW(LpB, LtB, y0 + k + 8)
                SDWRITE(0, LpA, LtA)
            }

            READWIN(u & 1)

            // vertical with folded scales (gm = g/sqrt2, gs = g/2), split
            f2 M1 = {0.f, 0.f}, S21 = {0.f, 0.f};
            f2 M2 = {0.f, 0.f}, S22 = {0.f, 0.f};
            #pragma unroll
            for (int j = 0; j < 6; ++j) {
                M1  = ffma2((f2){gw.gm[j], gw.gm[j]}, hA[(u + j) % KS], M1);
                S21 = ffma2((f2){gw.gs[j], gw.gs[j]}, hB[(u + j) % KS], S21);
            }
            #pragma unroll
            for (int j = 6; j < KS; ++j) {
                M2  = ffma2((f2){gw.gm[j], gw.gm[j]}, hA[(u + j) % KS], M2);
                S22 = ffma2((f2){gw.gs[j], gw.gs[j]}, hB[(u + j) % KS], S22);
            }
            const f2 M = M1 + M2, S2 = S21 + S22;
            const float xs = M.x * M.x, xd = M.y * M.y;
            const float a  = xs - xd;              // 2 mu1 mu2
            const float b  = xs + xd;              // mu1^2 + mu2^2
            const float p  = S2.x - S2.y;          // 2 E[pt]
            const float q  = S2.x + S2.y;          // E[p^2] + E[t^2]
            const float num = (a + C1) * (p - a + C2);
            const float den = (b + C1) * (q - b + C2);
            const float val = num * __builtin_amdgcn_rcpf(den);
            // mask output rows beyond the image (block y=11 covers 484..527)
            acc += (y0 + k < IMH) ? val : 0.f;

            HCONV(u % KS)
        }
    }
#undef LOADROW
#undef SDWRITE
#undef READWIN
#undef HTAPa
#undef HTAPb
#undef HCONV

    // Block reduction: wave shfl, then cross-wave via tiny LDS.
    #pragma unroll
    for (int off = 32; off > 0; off >>= 1) acc += __shfl_down(acc, off, 64);
    if (lane == 0) wsum[wid] = acc;
    __syncthreads();
    if (tid == 0) {
        atomicAdd(partial, wsum[0] + wsum[1] + wsum[2] + wsum[3]);
    }
}

__global__ void ssim_final_kernel(const float* __restrict__ partial,
                                  float* __restrict__ out, float invN)
{
    out[0] = 1.f - partial[0] * invN;
}

extern "C" void kernel_launch(void* const* d_in, const int* in_sizes, int n_in,
                              void* d_out, int out_size, void* d_ws, size_t ws_size,
                              hipStream_t stream) {
    const float* pred   = (const float*)d_in[0];
    const float* target = (const float*)d_in[1];
    float* out = (float*)d_out;
    float* partial = (float*)d_ws;

    const int B = 16, C = 3;
    const float invN = 1.0f / ((float)B * C * IMH * IMW);

    // separable 1-D Gaussian, same formula as reference (sigma=1.5, 11 taps)
    GWargs gw;
    {
        float s = 0.f;
        for (int i = 0; i < KS; ++i) {
            double e = exp(-((double)((i - 5) * (i - 5))) / (2.0 * 1.5 * 1.5));
            gw.g[i] = (float)e;
            s += gw.g[i];
        }
        for (int i = 0; i < KS; ++i) {
            gw.g[i]  /= s;
            gw.gm[i]  = gw.g[i] * 0.70710678118654752f;   // g / sqrt(2)
            gw.gs[i]  = gw.g[i] * 0.5f;                   // g / 2
        }
    }

    hipMemsetAsync(partial, 0, sizeof(float), stream);

    dim3 grid(IMW / 256, GRIDY, B * C);   // 2 x 12 x 48 = 1152 blocks
    dim3 block(256);
    ssim_col_kernel<<<grid, block, 0, stream>>>(pred, target, partial, gw);
    ssim_final_kernel<<<1, 1, 0, stream>>>(partial, out, invN);
}

// Round 21
// 62.920 us; speedup vs baseline: 1.0332x; 1.0255x over previous
//
#include <hip/hip_runtime.h>
#include <math.h>

#define KS 11
#define CHUNK 33      // output rows per block = 3 x 11 (static ring phases)
#define GRIDY 16      // 16*33 = 528 >= 512; tail rows masked out of the sum
#define IMW 512
#define IMH 512

// g: 11-tap Gaussian (h-conv, uniform scalar weights);
// gm = g/sqrt(2) (vertical mean chain), gs = g/2 (vertical second-moment chain)
struct GWargs { float g[KS]; float gm[KS]; float gs[KS]; };

typedef int   v4i __attribute__((ext_vector_type(4)));
typedef float f2  __attribute__((ext_vector_type(2)));
typedef float f4  __attribute__((ext_vector_type(4)));

// CK-style direct binding to the raw buffer load intrinsic.
__device__ f2 raw_buf_load_v2(v4i srsrc, int voffset, int soffset, int aux)
    __asm("llvm.amdgcn.raw.buffer.load.v2f32");

// SRD over ONE image row. nrec = IMW*4 for valid rows, 0 for out-of-image
// rows (all loads return 0 -> vertical zero-padding, branchless). Horizontal
// zero-padding: per-dword bounds checks. p=t=0 -> s=d=0 under the transform.
__device__ inline v4i make_row_srd(const float* row, int nrec) {
    union { const float* p; unsigned u[2]; } a; a.p = row;
    v4i r;
    r.x = (int)a.u[0];
    r.y = (int)a.u[1];
    r.z = nrec;             // num_records (bytes, stride==0)
    r.w = 0x00020000;       // raw untyped dword access
    return r;
}

__device__ inline f2 ffma2(f2 a, f2 b, f2 c) {
    return __builtin_elementwise_fma(a, b, c);
}

// s/d-transformed SSIM (4 conv chains), wave-private LDS row cache storing
// f2 {s,d} per column; exact 11-col b64 windows (conflict-free). All four
// FMA chains tree-split into two halves. CHUNK 33 / 1536 blocks = the
// untested optimum of the waves-vs-redundancy curve (6 waves/SIMD nominal
// at 1.30 ingests/output).
__global__ __launch_bounds__(256, 1) void ssim_col_kernel(
    const float* __restrict__ pred, const float* __restrict__ target,
    float* __restrict__ partial, GWargs gw)
{
    const int tid  = threadIdx.x;
    const int wid  = tid >> 6;
    const int lane = tid & 63;
    const int x    = blockIdx.x * 256 + tid;        // output column, 0..511
    const int wx0  = blockIdx.x * 256 + wid * 64;   // wave's first column
    const int y0   = blockIdx.y * CHUNK;            // first output row
    const int bc   = blockIdx.z;
    const float* pimg = pred   + (size_t)bc * (IMH * IMW);
    const float* timg = target + (size_t)bc * (IMH * IMW);

    // [wave][parity][f2 {s,d} of col E+i], E = wx0-8; 128 cols per row
    __shared__ f2 rbuf[4][2][128];     // 8 KiB
    __shared__ float wsum[4];

    // coalesced global byte offset: lane loads cols E+2*lane, E+2*lane+1
    const int vgb = (wx0 - 8 + 2 * lane) * 4;
    // f2 index of window start: col x-5 = E + (lane+3)
    const int w0 = lane + 3;

    // ring: hA = {h(s),h(d)}, hB = {h(s^2),h(d^2)}; slot(row r) = (r-y0+5)%11
    f2 hA[KS], hB[KS];

#define LOADROW(LP, LT, YI)                                                 \
    {                                                                       \
        const int yi = (YI);                                                \
        const int nrec = ((unsigned)yi < (unsigned)IMH) ? (IMW * 4) : 0;    \
        const int yc = yi < 0 ? 0 : (yi > IMH - 1 ? IMH - 1 : yi);          \
        const v4i ps = make_row_srd(pimg + (size_t)yc * IMW, nrec);         \
        const v4i ts = make_row_srd(timg + (size_t)yc * IMW, nrec);         \
        LP = raw_buf_load_v2(ps, vgb, 0, 0);                                \
        LT = raw_buf_load_v2(ts, vgb, 0, 0);                                \
    }

    // pack two columns of {p,t} into {s0,d0,s1,d1} and store as one f4
#define SDWRITE(PAR, LP, LT)                                                \
    *(f4*)&rbuf[wid][PAR][2 * lane] =                                       \
        (f4){(LP).x + (LT).x, (LP).x - (LT).x,                              \
             (LP).y + (LT).y, (LP).y - (LT).y};

    // read the exact 11-f2 window of parity PAR into F0..F10 (locals)
#define READWIN(PAR)                                                        \
        const f2* rb_ = &rbuf[wid][PAR][w0];                                \
        const f2 F0 = rb_[0], F1 = rb_[1], F2 = rb_[2], F3 = rb_[3];        \
        const f2 F4 = rb_[4], F5 = rb_[5], F6 = rb_[6], F7 = rb_[7];        \
        const f2 F8 = rb_[8], F9 = rb_[9], F10 = rb_[10];

#define HTAPa(F, J)                                                         \
    {   const f2 gj = {gw.g[J], gw.g[J]};                                   \
        A1 = ffma2(gj, F, A1);  B1 = ffma2(gj, F * F, B1); }
#define HTAPb(F, J)                                                         \
    {   const f2 gj = {gw.g[J], gw.g[J]};                                   \
        A2 = ffma2(gj, F, A2);  B2 = ffma2(gj, F * F, B2); }

    // h-conv F0..F10 into ring slot S; two half-chains + combine
#define HCONV(S)                                                            \
    {                                                                       \
        f2 A1, B1, A2, B2;                                                  \
        {   const f2 g0 = {gw.g[0], gw.g[0]};                               \
            A1 = g0 * F0; B1 = A1 * F0; }                                   \
        {   const f2 g6 = {gw.g[6], gw.g[6]};                               \
            A2 = g6 * F6; B2 = A2 * F6; }                                   \
        HTAPa(F1, 1)  HTAPa(F2, 2)  HTAPa(F3, 3)                            \
        HTAPa(F4, 4)  HTAPa(F5, 5)                                          \
        HTAPb(F7, 7)  HTAPb(F8, 8)  HTAPb(F9, 9)  HTAPb(F10, 10)            \
        hA[S] = A1 + A2; hB[S] = B1 + B2;                                   \
    }

    // Prologue: rows y0-5 .. y0+5 into slots 0..10 (same-step round trip,
    // one-time cost).
    f2 LpA, LtA, LpB, LtB;
    #pragma unroll
    for (int i = 0; i < KS; ++i) {
        LOADROW(LpA, LtA, y0 - 5 + i)
        SDWRITE(i & 1, LpA, LtA)
        { READWIN(i & 1) HCONV(i) }
    }
    // Pipeline priming: buf[0] <- row y0+6 ; regset1 <- row y0+7.
    LOADROW(LpA, LtA, y0 + 6)
    SDWRITE(0, LpA, LtA)
    LOADROW(LpB, LtB, y0 + 7)

    const float C1 = 1e-4f, C2 = 9e-4f;
    float acc = 0.f;

    // Main step u (output row y0+u):
    //  1. issue global loads for row u+8 into regset u&1
    //  2. ds_write regset (u+1)&1 (row u+7, loaded last step) -> buf[(u+1)&1]
    //  3. read row u+6's 11-col window from buf[u&1] (written last step)
    //  4. vertical + SSIM for output u (covers the reads; split chains)
    //  5. h-conv F -> ring slot u%11
    #pragma unroll
    for (int u = 0; u < CHUNK; ++u) {
        if ((u & 1) == 0) {
            LOADROW(LpA, LtA, y0 + u + 8)
            SDWRITE(1, LpB, LtB)
        } else {
            LOADROW(LpB, LtB, y0 + u + 8)
            SDWRITE(0, LpA, LtA)
        }

        READWIN(u & 1)

        // vertical with folded scales (gm = g/sqrt2, gs = g/2), split chains
        f2 M1 = {0.f, 0.f}, S21 = {0.f, 0.f};
        f2 M2 = {0.f, 0.f}, S22 = {0.f, 0.f};
        #pragma unroll
        for (int j = 0; j < 6; ++j) {
            M1  = ffma2((f2){gw.gm[j], gw.gm[j]}, hA[(u + j) % KS], M1);
            S21 = ffma2((f2){gw.gs[j], gw.gs[j]}, hB[(u + j) % KS], S21);
        }
        #pragma unroll
        for (int j = 6; j < KS; ++j) {
            M2  = ffma2((f2){gw.gm[j], gw.gm[j]}, hA[(u + j) % KS], M2);
            S22 = ffma2((f2){gw.gs[j], gw.gs[j]}, hB[(u + j) % KS], S22);
        }
        const f2 M = M1 + M2, S2 = S21 + S22;
        const float xs = M.x * M.x, xd = M.y * M.y;
        const float a  = xs - xd;              // 2 mu1 mu2
        const float b  = xs + xd;              // mu1^2 + mu2^2
        const float p  = S2.x - S2.y;          // 2 E[pt]
        const float q  = S2.x + S2.y;          // E[p^2] + E[t^2]
        const float num = (a + C1) * (p - a + C2);
        const float den = (b + C1) * (q - b + C2);
        const float val = num * __builtin_amdgcn_rcpf(den);
        // mask output rows beyond the image (block y=15 covers 495..527)
        acc += (y0 + u < IMH) ? val : 0.f;

        HCONV(u % KS)
    }
#undef LOADROW
#undef SDWRITE
#undef READWIN
#undef HTAPa
#undef HTAPb
#undef HCONV

    // Block reduction: wave shfl, then cross-wave via tiny LDS.
    #pragma unroll
    for (int off = 32; off > 0; off >>= 1) acc += __shfl_down(acc, off, 64);
    if (lane == 0) wsum[wid] = acc;
    __syncthreads();
    if (tid == 0) {
        atomicAdd(partial, wsum[0] + wsum[1] + wsum[2] + wsum[3]);
    }
}

__global__ void ssim_final_kernel(const float* __restrict__ partial,
                                  float* __restrict__ out, float invN)
{
    out[0] = 1.f - partial[0] * invN;
}

extern "C" void kernel_launch(void* const* d_in, const int* in_sizes, int n_in,
                              void* d_out, int out_size, void* d_ws, size_t ws_size,
                              hipStream_t stream) {
    const float* pred   = (const float*)d_in[0];
    const float* target = (const float*)d_in[1];
    float* out = (float*)d_out;
    float* partial = (float*)d_ws;

    const int B = 16, C = 3;
    const float invN = 1.0f / ((float)B * C * IMH * IMW);

    // separable 1-D Gaussian, same formula as reference (sigma=1.5, 11 taps)
    GWargs gw;
    {
        float s = 0.f;
        for (int i = 0; i < KS; ++i) {
            double e = exp(-((double)((i - 5) * (i - 5))) / (2.0 * 1.5 * 1.5));
            gw.g[i] = (float)e;
            s += gw.g[i];
        }
        for (int i = 0; i < KS; ++i) {
            gw.g[i]  /= s;
            gw.gm[i]  = gw.g[i] * 0.70710678118654752f;   // g / sqrt(2)
            gw.gs[i]  = gw.g[i] * 0.5f;                   // g / 2
        }
    }

    hipMemsetAsync(partial, 0, sizeof(float), stream);

    dim3 grid(IMW / 256, GRIDY, B * C);   // 2 x 16 x 48 = 1536 blocks
    dim3 block(256);
    ssim_col_kernel<<<grid, block, 0, stream>>>(pred, target, partial, gw);
    ssim_final_kernel<<<1, 1, 0, stream>>>(partial, out, invN);
}